// Round 7
// baseline (123.192 us; speedup 1.0000x reference)
//
#include <hip/hip_runtime.h>

// LengthRegulator: B=16, S=512, D=384, MAX_DUR=8 -> max_len=4096
// out[b,t,:] = emb[b, searchsorted_right(cumsum(dur[b]), t), :] if t < total else 0
//
// K1 (256 blocks, 16/batch): wave-0 shfl-scan of the 512 durations (redundant
//     per block — parallel and cheap), then each of 256 threads binary-searches
//     exactly 1 output slot -> idxmap (-1 = zeros). ~1 us.
// K2 (1536 blocks): 16 float4 per thread. XCD-aware swizzle: xcd = blk&7,
//     batch = xcd + 8*(w&1) -> each XCD serves 2 batches, 1.5 MB emb working
//     set < 4 MB L2 (R6: -3.3 us). Plain stores (NT regressed R4: bypassing
//     L2 defeats 64B write-combining).

#define BB 16
#define SS 512
#define DD 384
#define D4 (DD / 4)          // 96 float4 per row
#define MAXLEN 4096          // S * MAX_DUR
#define BATCH_F4 (MAXLEN * D4)      // 393216 float4 per batch
#define K2_ITERS 16
#define K2_CHUNK (256 * K2_ITERS)   // 4096 float4 per block
#define CHUNKS_PER_B (BATCH_F4 / K2_CHUNK)  // 96

typedef float f32x4 __attribute__((ext_vector_type(4)));

// ---- K1: cumsum + searchsorted, 16 blocks per batch, 1 slot per thread ----
__global__ __launch_bounds__(256)
void lr_prologue_kernel(const int* __restrict__ dur, int* __restrict__ idxmap) {
    __shared__ int cs[SS];
    const int b     = blockIdx.x >> 4;
    const int piece = blockIdx.x & 15;
    const int tid   = threadIdx.x;

    // wave 0: inclusive scan of dur[b, :] into LDS
    if (tid < 64) {
        const int* drow = dur + b * SS + tid * 8;
        int loc[8];
        int run = 0;
        #pragma unroll
        for (int j = 0; j < 8; ++j) { run += drow[j]; loc[j] = run; }
        int sc = run;
        #pragma unroll
        for (int off = 1; off < 64; off <<= 1) {
            int n = __shfl_up(sc, off, 64);
            if (tid >= off) sc += n;
        }
        const int base = sc - run;
        #pragma unroll
        for (int j = 0; j < 8; ++j) cs[tid * 8 + j] = base + loc[j];
    }
    __syncthreads();

    const int total = cs[SS - 1];
    const int t = piece * 256 + tid;
    // guarded while-loop REQUIRED: fixed 9-step unroll corrupts lo when the
    // interval converges early (R3 correctness failure).
    int lo = 0, hi = SS;
    while (lo < hi) {
        int mid = (lo + hi) >> 1;
        if (cs[mid] <= t) lo = mid + 1; else hi = mid;
    }
    if (lo > SS - 1) lo = SS - 1;                // jnp.clip
    idxmap[b * MAXLEN + t] = (t < total) ? lo : -1;
}

// ---- K2: gather, 16 float4 per thread, XCD-swizzled batch mapping ----
__global__ __launch_bounds__(256)
void lr_gather_kernel(const f32x4* __restrict__ emb,
                      const int* __restrict__ idxmap,
                      f32x4* __restrict__ out) {
    const unsigned x   = blockIdx.x;
    const unsigned xcd = x & 7;          // round-robin XCD assignment
    const unsigned w   = x >> 3;         // 0..191 within this XCD
    const unsigned b   = xcd + 8u * (w & 1);   // 2 batches per XCD
    const unsigned c   = w >> 1;         // chunk 0..95 within batch

    const unsigned local0 = c * K2_CHUNK + threadIdx.x;   // f4 idx within batch
    const f32x4* embb = emb + b * (SS * D4);
    const int* imap   = idxmap + b * MAXLEN;
    f32x4* outb       = out + (size_t)b * BATCH_F4;

    #pragma unroll
    for (int k = 0; k < K2_ITERS; ++k) {
        const unsigned local = local0 + k * 256;
        const unsigned bt = local / D4;              // magic-mul const div
        const unsigned d4 = local - bt * D4;
        const int idx = imap[bt];
        f32x4 v = {0.f, 0.f, 0.f, 0.f};
        if (idx >= 0) v = embb[(unsigned)idx * D4 + d4];
        outb[local] = v;
    }
}

extern "C" void kernel_launch(void* const* d_in, const int* in_sizes, int n_in,
                              void* d_out, int out_size, void* d_ws, size_t ws_size,
                              hipStream_t stream) {
    const float* text_emb  = (const float*)d_in[0];  // (16,512,384) f32
    const int*   durations = (const int*)d_in[1];    // (16,512) i32
    float* out = (float*)d_out;                      // (16,4096,384) f32

    int* idxmap = (int*)d_ws;                        // B*MAXLEN ints = 256 KB

    lr_prologue_kernel<<<BB * 16, 256, 0, stream>>>(durations, idxmap);

    lr_gather_kernel<<<BB * CHUNKS_PER_B, 256, 0, stream>>>(
        (const f32x4*)text_emb, idxmap, (f32x4*)out);
}

// Round 8
// 118.413 us; speedup vs baseline: 1.0404x; 1.0404x over previous
//
#include <hip/hip_runtime.h>

// LengthRegulator: B=16, S=512, D=384, MAX_DUR=8 -> max_len=4096
// out[b,t,:] = emb[b, searchsorted_right(cumsum(dur[b]), t), :] if t < total else 0
//
// R6 structure (best: 120.1 us) + int16 idxmap (halves map traffic).
// K1 (64 blocks, 4/batch): wave-0 shfl-scan of the 512 durations, then 256
//     threads binary-search 1024 output slots -> idxmap (-1 = zeros).
// K2 (3072 blocks): 8 float4 per thread. XCD-aware swizzle: xcd = blk&7,
//     batch = xcd + 8*(w&1) -> each XCD serves 2 batches, 1.5 MB emb working
//     set < 4 MB L2 (R6: -3.3 us vs none). Plain stores (NT regressed R4:
//     bypassing L2 defeats 64B write-combining). 8 iters/thread, 3072 blocks
//     (16 iters/1536 blocks regressed R7: less TLP for the memory system).

#define BB 16
#define SS 512
#define DD 384
#define D4 (DD / 4)          // 96 float4 per row
#define MAXLEN 4096          // S * MAX_DUR
#define BATCH_F4 (MAXLEN * D4)      // 393216 float4 per batch
#define K2_ITERS 8
#define K2_CHUNK (256 * K2_ITERS)   // 2048 float4 per block
#define CHUNKS_PER_B (BATCH_F4 / K2_CHUNK)  // 192

typedef float f32x4 __attribute__((ext_vector_type(4)));

// ---- K1: cumsum + searchsorted, 4 blocks per batch ----
__global__ __launch_bounds__(256)
void lr_prologue_kernel(const int* __restrict__ dur, short* __restrict__ idxmap) {
    __shared__ int cs[SS];
    const int b       = blockIdx.x >> 2;
    const int quarter = blockIdx.x & 3;
    const int tid     = threadIdx.x;

    // wave 0: inclusive scan of dur[b, :] into LDS
    if (tid < 64) {
        const int* drow = dur + b * SS + tid * 8;
        int loc[8];
        int run = 0;
        #pragma unroll
        for (int j = 0; j < 8; ++j) { run += drow[j]; loc[j] = run; }
        int sc = run;
        #pragma unroll
        for (int off = 1; off < 64; off <<= 1) {
            int n = __shfl_up(sc, off, 64);
            if (tid >= off) sc += n;
        }
        const int base = sc - run;
        #pragma unroll
        for (int j = 0; j < 8; ++j) cs[tid * 8 + j] = base + loc[j];
    }
    __syncthreads();

    const int total = cs[SS - 1];
    short* omap = idxmap + b * MAXLEN + quarter * 1024;
    for (int k = 0; k < 4; ++k) {
        const int t = quarter * 1024 + k * 256 + tid;
        // guarded while-loop REQUIRED: fixed 9-step unroll corrupts lo when
        // the interval converges early (R3 correctness failure).
        int lo = 0, hi = SS;
        while (lo < hi) {
            int mid = (lo + hi) >> 1;
            if (cs[mid] <= t) lo = mid + 1; else hi = mid;
        }
        if (lo > SS - 1) lo = SS - 1;            // jnp.clip
        omap[k * 256 + tid] = (short)((t < total) ? lo : -1);
    }
}

// ---- K2: gather, 8 float4 per thread, XCD-swizzled batch mapping ----
__global__ __launch_bounds__(256)
void lr_gather_kernel(const f32x4* __restrict__ emb,
                      const short* __restrict__ idxmap,
                      f32x4* __restrict__ out) {
    const unsigned x   = blockIdx.x;
    const unsigned xcd = x & 7;          // round-robin XCD assignment
    const unsigned w   = x >> 3;         // 0..383 within this XCD
    const unsigned b   = xcd + 8u * (w & 1);   // 2 batches per XCD
    const unsigned c   = w >> 1;         // chunk 0..191 within batch

    const unsigned local0 = c * K2_CHUNK + threadIdx.x;   // f4 idx within batch
    const f32x4* embb = emb + b * (SS * D4);
    const short* imap = idxmap + b * MAXLEN;
    f32x4* outb       = out + (size_t)b * BATCH_F4;

    #pragma unroll
    for (int k = 0; k < K2_ITERS; ++k) {
        const unsigned local = local0 + k * 256;
        const unsigned bt = local / D4;              // magic-mul const div
        const unsigned d4 = local - bt * D4;
        const int idx = (int)imap[bt];
        f32x4 v = {0.f, 0.f, 0.f, 0.f};
        if (idx >= 0) v = embb[(unsigned)idx * D4 + d4];
        outb[local] = v;
    }
}

extern "C" void kernel_launch(void* const* d_in, const int* in_sizes, int n_in,
                              void* d_out, int out_size, void* d_ws, size_t ws_size,
                              hipStream_t stream) {
    const float* text_emb  = (const float*)d_in[0];  // (16,512,384) f32
    const int*   durations = (const int*)d_in[1];    // (16,512) i32
    float* out = (float*)d_out;                      // (16,4096,384) f32

    short* idxmap = (short*)d_ws;                    // B*MAXLEN shorts = 128 KB

    lr_prologue_kernel<<<BB * 4, 256, 0, stream>>>(durations, idxmap);

    lr_gather_kernel<<<BB * CHUNKS_PER_B, 256, 0, stream>>>(
        (const f32x4*)text_emb, idxmap, (f32x4*)out);
}